// Round 11
// baseline (975.779 us; speedup 1.0000x reference)
//
#include <hip/hip_runtime.h>
#include <hip/hip_bf16.h>
#include <hip/hip_cooperative_groups.h>

// 2-layer GCN encoder: (GCNConv -> BatchNorm1d(train) -> PReLU) x 2
// N=50000, E=800000, D=128. Inputs f32 (probed), edge_index int64 (probed),
// output f32. Internal: buffers bf16, math f32.
//
// R24: SINGLE cooperative kernel (1 dispatch, 7 grid.sync) replacing 8
// dispatches. Theory: ~100us of the 219us total is inter-dispatch overhead
// (kernel work ledger sums to ~115us; per-kernel optimizations repeatedly
// under-delivered by the same residual). Phases:
//  P0 zero tailc/stats1p/stats2p + W1/W2 swizzle       (was memset+part of bin)
//  P1 bin 1000x800-edge chunks -> binned (196 buckets) (R20 format)
//  P2 degfill per 256-node bucket -> CSR/dinv          (R20 format)
//  P3 gemm L1 (global-B: W read from L2-resident wp1; no 32KB LDS tile)
//  P4 agg L1 (R19 16-deep scalar-pipe gather; wave-strided; reg-acc stats)
//  P5 gemm L2 (XMODE2: BN1+PReLU fused in A-path)
//  P6 agg L2
//  P7 bn_apply -> d_out
// LDS ~12KB total -> occupancy wave-capped; __launch_bounds__(256,6) = 24
// waves/CU (~= R19 agg's 23). Grid from hipOccupancyMaxActiveBlocksPerMP
// (host query, capture-safe) so cooperative launch can't oversubscribe.
//
// ws layout (bytes) -- R20-compatible:
//   [0       .. +200000)   dinv f32[NN]
//   [201728  .. +784)      tailc int[196]
//   [404800  .. +200000)   rowptr int[NN]
//   [604816  .. +200000)   rowend int[NN]
//   [806400  .. +65536)    stats1p f32[64][256]
//   [871936  .. +65536)    stats2p f32[64][256]
//   [1048576 .. +3.6MB)    csr_src int[196*4608]
//   [4718592 .. +12.8MB)   hbuf  u32[NN*64] packed-slot (dinv-scaled)
//   [17518592.. +32768)    wp1 bf16[128*128] swizzled
//   [17551360.. +32768)    wp2 bf16[128*128] swizzled
//   [30056448.. +12.8MB)   aggbuf bf16[NN*DD] row-major
//   [42856448.. +3.6MB)    binned uint[196*4608] packed (src<<16)|dst

namespace cg = cooperative_groups;

typedef __hip_bfloat16 bf16;
typedef __attribute__((ext_vector_type(8))) short short8;   // 8 bf16 = 4 VGPR
typedef __attribute__((ext_vector_type(4))) float f32x4;    // MFMA accumulator

#define NN 50000
#define NE 800000
#define DD 128
#define BN_EPS 1e-5f
#define NCHUNK 1000      // bin virtual chunks
#define CHUNKE 800       // edges per chunk (NE/NCHUNK exactly)
#define CAP 4608         // per-bucket capacity (mean 4096 + 8 sigma)
#define NBKT 196         // ceil(50000 / 256)
#define NB_G 782         // ceil(NN / 64) gemm virtual blocks

__device__ __forceinline__ float b2f(bf16 v) { return __bfloat162float(v); }
__device__ __forceinline__ float ldf(const void* p, size_t idx, int isbf) {
  return isbf ? b2f(((const bf16*)p)[idx]) : ((const float*)p)[idx];
}
__device__ __forceinline__ int lde(const void* ei, size_t idx, int is64) {
  return is64 ? (int)((const long long*)ei)[idx] : ((const int*)ei)[idx];
}
__device__ __forceinline__ unsigned int f2bs(float v) {
  bf16 b = __float2bfloat16(v);
  return (unsigned int)*reinterpret_cast<unsigned short*>(&b);
}
__device__ __forceinline__ float bslo(unsigned int u) { return __uint_as_float(u << 16); }
__device__ __forceinline__ float bshi(unsigned int u) { return __uint_as_float(u & 0xFFFF0000u); }
__device__ __forceinline__ float s2f(short v) {
  return __uint_as_float(((unsigned int)(unsigned short)v) << 16);
}

__global__ __launch_bounds__(256, 6) void k_fused(
    const void* x, const int* ei_i, const void* W1, const void* b1,
    const void* g1, const void* be1, const void* a1, const void* W2,
    const void* b2, const void* g2, const void* be2, const void* a2,
    char* w, void* dout) {
  float* dinv = (float*)w;
  int* tailc = (int*)(w + 201728);
  int* rowptr = (int*)(w + 404800);
  int* rowend = (int*)(w + 604816);
  float* stats1p = (float*)(w + 806400);
  float* stats2p = (float*)(w + 871936);
  int* csr_src = (int*)(w + 1048576);
  unsigned int* hbuf = (unsigned int*)(w + 4718592);
  unsigned short* wp1 = (unsigned short*)(w + 17518592);
  unsigned short* wp2 = (unsigned short*)(w + 17551360);
  unsigned short* aggbuf = (unsigned short*)(w + 30056448);
  unsigned int* binned = (unsigned int*)(w + 42856448);

  cg::grid_group grid = cg::this_grid();
  const int tid = threadIdx.x;
  const int bid = blockIdx.x;
  const int nb = gridDim.x;

  __shared__ int s_cnt[NBKT], s_cur[NBKT], s_gb[NBKT];     // 2.3 KB
  __shared__ unsigned int s_ebuf[CHUNKE];                  // 3.2 KB
  __shared__ int s_hist[256];                              // 1 KB
  __shared__ float rs1[256], rq1[256], rs2[256], rq2[256]; // 4 KB
  __shared__ float sSc[DD], sSh[DD], sAl[1];               // 1 KB
  __shared__ int sflags[2];

  // ---- per-block dtype self-probe ----
  if (tid < 64) {
    unsigned long long m1 = __ballot(ei_i[2 * tid + 1] != 0);
    int ex = (((const unsigned short*)x)[2 * tid] >> 7) & 0xFF;
    unsigned long long m2 = __ballot(ex >= 90 && ex <= 140);
    if (tid == 0) {
      sflags[0] = (m1 == 0ull) ? 1 : 0;
      sflags[1] = (__popcll(m2) >= 48) ? 1 : 0;
    }
  }
  __syncthreads();
  const int is64 = sflags[0], isbf = sflags[1];

  // ---- P0: zero tailc + stats; swizzle W1/W2 ----
  {
    const int g0 = bid * 256 + tid, gs = nb * 256;
    if (g0 < NBKT) tailc[g0] = 0;
    for (int i = g0; i < 16384; i += gs) {
      stats1p[i] = 0.f;
      stats2p[i] = 0.f;
    }
    for (int i = g0; i < 16384; i += gs) {
      int k = i >> 7, n = i & 127;
      int dsti = (k >> 3) * 1024 + n * 8 + (k & 7);
      wp1[dsti] = (unsigned short)f2bs(ldf(W1, i, isbf));
      wp2[dsti] = (unsigned short)f2bs(ldf(W2, i, isbf));
    }
  }
  grid.sync();

  // ---- P1: bin edges into 196 buckets ----
  for (int vc = bid; vc < NCHUNK; vc += nb) {
    __syncthreads();
    if (tid < NBKT) { s_cnt[tid] = 0; s_cur[tid] = 0; }
    __syncthreads();
    const int e0 = vc * CHUNKE;
    for (int t = tid; t < CHUNKE; t += 256) {
      int s = lde(ei_i, (size_t)(e0 + t), is64);
      int d = lde(ei_i, (size_t)NE + e0 + t, is64);
      s_ebuf[t] = ((unsigned)s << 16) | (unsigned)d;
      atomicAdd(&s_cnt[d >> 8], 1);
    }
    __syncthreads();
    if (tid < NBKT && s_cnt[tid] > 0)
      s_gb[tid] = tid * CAP + atomicAdd(&tailc[tid], s_cnt[tid]);
    __syncthreads();
    for (int t = tid; t < CHUNKE; t += 256) {
      unsigned int u = s_ebuf[t];
      int b = (int)((u >> 8) & 0xFF);
      int r = atomicAdd(&s_cur[b], 1);
      binned[s_gb[b] + r] = u;
    }
  }
  grid.sync();

  // ---- P2: per-bucket degree hist -> dinv/rowptr/rowend -> CSR fill ----
  for (int vb = bid; vb < NBKT; vb += nb) {
    __syncthreads();
    s_hist[tid] = 0;
    __syncthreads();
    const int eb = vb * CAP, ee = eb + tailc[vb];
    for (int e = eb + tid; e < ee; e += 256) atomicAdd(&s_hist[binned[e] & 0xFF], 1);
    __syncthreads();
    int h = s_hist[tid];
    __syncthreads();
    for (int off = 1; off < 256; off <<= 1) {  // inclusive scan over 256
      int u2 = (tid >= off) ? s_hist[tid - off] : 0;
      __syncthreads();
      s_hist[tid] += u2;
      __syncthreads();
    }
    int start = eb + s_hist[tid] - h;
    int node = vb * 256 + tid;
    if (node < NN) {
      rowptr[node] = start;
      rowend[node] = start + h;
      dinv[node] = rsqrtf((float)(h + 1));  // +1 self-loop
    }
    __syncthreads();
    s_hist[tid] = start;  // repurpose as fill cursor
    __syncthreads();
    for (int e = eb + tid; e < ee; e += 256) {
      unsigned int u = binned[e];
      int pos = atomicAdd(&s_hist[u & 0xFF], 1);
      csr_src[pos] = (int)(u >> 16);
    }
  }
  grid.sync();

  const int wave = tid >> 6;
  const int lane = tid & 63;
  const int quad = lane >> 4;
  const int m16 = lane & 15;

  // ---- gemm phase (shared by P3/P5), B read from global wp (L2-hot) ----
  auto gemm_phase = [&](auto xmode2, const void* in_, const unsigned short* wp,
                        const float* statsp, const void* g, const void* be,
                        const void* al, unsigned int* outp) {
    constexpr bool XM2 = decltype(xmode2)::value;
    if (XM2) {
      if (tid < DD) {
        float s = 0.f, q = 0.f;
#pragma unroll 8
        for (int k = 0; k < 64; k++) {
          s += statsp[k * 256 + tid];
          q += statsp[k * 256 + 128 + tid];
        }
        const float inv_n = 1.0f / NN;
        float mu = s * inv_n;
        float var = q * inv_n - mu * mu;
        float sc = rsqrtf(var + BN_EPS) * ldf(g, tid, isbf);
        sSc[tid] = sc;
        sSh[tid] = ldf(be, tid, isbf) - mu * sc;
      }
      if (tid == 0) sAl[0] = ldf(al, 0, isbf);
    }
    __syncthreads();
    const float alv = XM2 ? sAl[0] : 0.f;
    for (int vb = bid; vb < NB_G; vb += nb) {
      const int r0 = vb * 64 + wave * 16;
      f32x4 acc[8];
#pragma unroll
      for (int n = 0; n < 8; n++) acc[n] = (f32x4){0.f, 0.f, 0.f, 0.f};
#pragma unroll
      for (int q = 0; q < 4; q++) {
        const int kq = q * 32 + quad * 8;
        short8 af;
        int row = r0 + m16;
        row = row < NN ? row : NN - 1;  // clamp; garbage rows never stored
        if (XM2) {
          short8 raw = *(const short8*)((const short*)in_ + (size_t)row * DD + kq);
          short8 f;
#pragma unroll
          for (int jj = 0; jj < 8; jj++) {
            float y = s2f(raw[jj]);
            y = y * sSc[kq + jj] + sSh[kq + jj];
            y = y > 0.f ? y : alv * y;
            f[jj] = (short)f2bs(y);
          }
          af = f;
        } else if (isbf) {
          af = *(const short8*)((const short*)in_ + (size_t)row * DD + kq);
        } else {
          const float* ap = (const float*)in_ + (size_t)row * DD + kq;
          const float4 u0 = *(const float4*)ap;
          const float4 u1 = *(const float4*)(ap + 4);
          float v[8] = {u0.x, u0.y, u0.z, u0.w, u1.x, u1.y, u1.z, u1.w};
          short8 f;
#pragma unroll
          for (int jj = 0; jj < 8; jj++) f[jj] = (short)f2bs(v[jj]);
          af = f;
        }
        const short* bp = (const short*)wp + (q * 4 + quad) * 1024 + m16 * 8;
#pragma unroll
        for (int n = 0; n < 8; n++) {
          const short8 bfrag = *(const short8*)(bp + n * 128);
          acc[n] = __builtin_amdgcn_mfma_f32_16x16x32_bf16(af, bfrag, acc[n], 0, 0, 0);
        }
      }
#pragma unroll
      for (int r = 0; r < 4; r++) {
        int row = r0 + quad * 4 + r;
        if (row < NN) {
          float di = dinv[row];
          unsigned int* orow = outp + (size_t)row * 64;
#pragma unroll
          for (int n = 0; n < 4; n++) {
            unsigned int p = (f2bs(di * acc[n + 4][r]) << 16) | f2bs(di * acc[n][r]);
            orow[n * 16 + m16] = p;
          }
        }
      }
    }
  };

  // ---- agg phase (shared by P4/P6): R19 16-deep scalar-pipe gather ----
  auto agg_phase = [&](const unsigned int* hs, const void* bias,
                       unsigned short* outp, float* statsp) {
    const int ws_ = nb * 4;
    float ts1 = 0.f, tq1 = 0.f, ts2 = 0.f, tq2 = 0.f;
    for (int wn = bid * 4 + wave; wn < NN; wn += ws_) {
      const float dd_ = dinv[wn];
      unsigned int hv = hs[(size_t)wn * 64 + lane];
      float ax = bslo(hv), ay = bshi(hv);
      int e = __builtin_amdgcn_readfirstlane(rowptr[wn]);
      const int e1 = __builtin_amdgcn_readfirstlane(rowend[wn]);
      for (; e + 16 <= e1; e += 16) {
        int s[16];
#pragma unroll
        for (int k = 0; k < 16; k++) s[k] = csr_src[e + k];
        unsigned int v[16];
#pragma unroll
        for (int k = 0; k < 16; k++) v[k] = hs[(size_t)s[k] * 64 + lane];
#pragma unroll
        for (int k = 0; k < 16; k++) { ax += bslo(v[k]); ay += bshi(v[k]); }
      }
      const int r = e1 - e;  // 0..15, wave-uniform
      if (r > 0) {
        int s[16];
#pragma unroll
        for (int k = 0; k < 16; k++) s[k] = csr_src[e + (k < r ? k : 0)];
        unsigned int v[16];
#pragma unroll
        for (int k = 0; k < 16; k++) v[k] = hs[(size_t)s[k] * 64 + lane];
#pragma unroll
        for (int k = 0; k < 16; k++) {
          const float m = (k < r) ? 1.f : 0.f;
          ax += m * bslo(v[k]);
          ay += m * bshi(v[k]);
        }
      }
      float o1 = dd_ * ax + ldf(bias, lane, isbf);
      float o2 = dd_ * ay + ldf(bias, lane + 64, isbf);
      unsigned short* orow = outp + (size_t)wn * DD;
      orow[lane] = (unsigned short)f2bs(o1);
      orow[lane + 64] = (unsigned short)f2bs(o2);
      ts1 += o1; tq1 += o1 * o1;
      ts2 += o2; tq2 += o2 * o2;
    }
    rs1[tid] = ts1; rq1[tid] = tq1;
    rs2[tid] = ts2; rq2[tid] = tq2;
    __syncthreads();
    float* p = statsp + (bid & 63) * 256;
    if (tid < 64) {
      float s = rs1[tid] + rs1[tid + 64] + rs1[tid + 128] + rs1[tid + 192];
      float q = rq1[tid] + rq1[tid + 64] + rq1[tid + 128] + rq1[tid + 192];
      atomicAdd(&p[tid], s);
      atomicAdd(&p[128 + tid], q);
    } else if (tid < 128) {
      int l = tid - 64;
      float s = rs2[l] + rs2[l + 64] + rs2[l + 128] + rs2[l + 192];
      float q = rq2[l] + rq2[l + 64] + rq2[l + 128] + rq2[l + 192];
      atomicAdd(&p[tid], s);
      atomicAdd(&p[128 + tid], q);
    }
    __syncthreads();
  };

  // ---- P3..P6 ----
  gemm_phase(std::integral_constant<bool, false>{}, x, wp1, nullptr, nullptr,
             nullptr, nullptr, hbuf);
  grid.sync();
  agg_phase(hbuf, b1, aggbuf, stats1p);
  grid.sync();
  gemm_phase(std::integral_constant<bool, true>{}, aggbuf, wp2, stats1p, g1,
             be1, a1, hbuf);
  grid.sync();
  agg_phase(hbuf, b2, aggbuf, stats2p);
  grid.sync();

  // ---- P7: BN2 + PReLU -> dout ----
  {
    if (tid < DD) {
      float s = 0.f, q = 0.f;
#pragma unroll 8
      for (int k = 0; k < 64; k++) {
        s += stats2p[k * 256 + tid];
        q += stats2p[k * 256 + 128 + tid];
      }
      const float inv_n = 1.0f / NN;
      float mu = s * inv_n;
      float var = q * inv_n - mu * mu;
      float sc = rsqrtf(var + BN_EPS) * ldf(g2, tid, isbf);
      sSc[tid] = sc;
      sSh[tid] = ldf(be2, tid, isbf) - mu * sc;
    }
    if (tid == 0) sAl[0] = ldf(a2, 0, isbf);
    __syncthreads();
    const float alpha = sAl[0];
    const unsigned int* x32 = (const unsigned int*)aggbuf;
    for (int i4 = bid * 256 + tid; i4 < NN * 32; i4 += nb * 256) {
      int jq = (i4 & 31) * 4;
      const uint2 xv = ((const uint2*)x32)[i4];
      float xa[4] = {bslo(xv.x), bshi(xv.x), bslo(xv.y), bshi(xv.y)};
      float y[4];
#pragma unroll
      for (int u = 0; u < 4; u++) {
        int j = jq + u;
        float v = xa[u] * sSc[j] + sSh[j];
        y[u] = v > 0.f ? v : alpha * v;
      }
      if (isbf) {
        uint2 o;
        o.x = (f2bs(y[1]) << 16) | f2bs(y[0]);
        o.y = (f2bs(y[3]) << 16) | f2bs(y[2]);
        ((uint2*)dout)[i4] = o;
      } else {
        float4 o = {y[0], y[1], y[2], y[3]};
        ((float4*)dout)[i4] = o;
      }
    }
  }
}

extern "C" void kernel_launch(void* const* d_in, const int* in_sizes, int n_in,
                              void* d_out, int out_size, void* d_ws, size_t ws_size,
                              hipStream_t stream) {
  const void* x = d_in[0];
  const int* ei = (const int*)d_in[1];
  const void* W1 = d_in[2];
  const void* b1 = d_in[3];
  const void* g1 = d_in[4];
  const void* be1 = d_in[5];
  const void* a1 = d_in[6];
  const void* W2 = d_in[7];
  const void* b2 = d_in[8];
  const void* g2 = d_in[9];
  const void* be2 = d_in[10];
  const void* a2 = d_in[11];
  char* w = (char*)d_ws;

  int maxb = 0;
  hipError_t oe = hipOccupancyMaxActiveBlocksPerMultiprocessor(
      &maxb, reinterpret_cast<const void*>(&k_fused), 256, 0);
  if (oe != hipSuccess || maxb < 1) maxb = 4;
  int grid = maxb * 256;  // 256 CUs on MI355X
  if (grid > 2048) grid = 2048;

  void* ka[] = {(void*)&x,  (void*)&ei,  (void*)&W1, (void*)&b1,
                (void*)&g1, (void*)&be1, (void*)&a1, (void*)&W2,
                (void*)&b2, (void*)&g2,  (void*)&be2, (void*)&a2,
                (void*)&w,  (void*)&d_out};
  hipLaunchCooperativeKernel(reinterpret_cast<const void*>(&k_fused),
                             dim3(grid), dim3(256), ka, 0, stream);
}

// Round 12
// 221.062 us; speedup vs baseline: 4.4140x; 4.4140x over previous
//
#include <hip/hip_runtime.h>
#include <hip/hip_bf16.h>

// 2-layer GCN encoder: (GCNConv -> BatchNorm1d(train) -> PReLU) x 2
// N=50000, E=800000, D=128. Inputs f32 (probed), edge_index int64 (probed),
// output f32. Internal: GEMM/agg buffers bf16, math f32.
//
// R25 = exact restore of the best-measured configuration (219.4us, measured
// twice: Round-6 and Round-10): R19 agg (16-deep scalar-pipe gather +
// predicated 16-remainder), R18 gemm (64 rows/block), original bin/degfill.
// Closed lines (all measured worse): R14 chunked agg (-90us), R16 uint4
// (-34us), R20 parallel front-end (neutral), R21 uint2 (-15us), R22 32-deep
// (-7us), R24 cooperative fusion (-1247us: co-residency cap killed agg TLP,
// global-B gemm tripled FETCH). This is the practical floor barring a new
// structural idea.
//
// ws layout (bytes):
//   [0       .. +200000)   dinv f32[NN]
//   [200704  .. +8)        flags: [0]=int64?, [1]=bf16-floats?
//   [404800  .. +200000)   rowptr int[NN] (row starts, gapped CSR)
//   [604816  .. +200000)   rowend int[NN]
//   [805632  .. +256)      tailc int[64] (zeroed by memset; bucket fill counts)
//   [806400  .. +65536)    stats1p f32[64][256]
//   [871936  .. +65536)    stats2p f32[64][256]
//   [1048576 .. +3.7MB)    csr_src int[49*CAP]
//   [4718592 .. +12.8MB)   hbuf  bf16[NN*DD] packed-slot layout (dinv-scaled)
//   [17518592.. +32768)    wp1 bf16[128*128] swizzled
//   [17551360.. +32768)    wp2 bf16[128*128] swizzled
//   [30056448.. +12.8MB)   aggbuf bf16[NN*DD] row-major
//   [42856448.. +3.7MB)    binned uint[49*CAP] packed

typedef __hip_bfloat16 bf16;
typedef __attribute__((ext_vector_type(8))) short short8;   // 8 bf16 = 4 VGPR
typedef __attribute__((ext_vector_type(4))) float f32x4;    // MFMA accumulator

#define NN 50000
#define NE 800000
#define DD 128
#define BN_EPS 1e-5f
#define BIN_CHUNK 3125   // NE / 256 exactly
#define CAP 18432        // per-bucket slot capacity (72*256; mu+16sigma)
#define NBKT 49          // ceil(50000 / 1024)

__device__ __forceinline__ float b2f(bf16 v) { return __bfloat162float(v); }
__device__ __forceinline__ float ldf(const void* p, size_t idx, int isbf) {
  return isbf ? b2f(((const bf16*)p)[idx]) : ((const float*)p)[idx];
}
__device__ __forceinline__ int lde(const void* ei, size_t idx, int is64) {
  return is64 ? (int)((const long long*)ei)[idx] : ((const int*)ei)[idx];
}
__device__ __forceinline__ unsigned int f2bs(float v) {
  bf16 b = __float2bfloat16(v);
  return (unsigned int)*reinterpret_cast<unsigned short*>(&b);
}
__device__ __forceinline__ float bslo(unsigned int u) { return __uint_as_float(u << 16); }
__device__ __forceinline__ float bshi(unsigned int u) { return __uint_as_float(u & 0xFFFF0000u); }
__device__ __forceinline__ float s2f(short v) {
  return __uint_as_float(((unsigned int)(unsigned short)v) << 16);
}

// 256 blocks x 256. Per-block dtype self-probe; block 0 publishes flags;
// blocks 0..63 swizzle W1, 64..127 swizzle W2; all bin their edge chunk into
// packed binned[] at zero-based bucket counters (tailc pre-zeroed).
__global__ __launch_bounds__(256) void k_bin(const int* ei_i, const unsigned short* x16,
                                             const void* W1, const void* W2,
                                             unsigned short* wp1, unsigned short* wp2,
                                             int* flags, int* tailc, unsigned int* binned) {
  __shared__ int cnt[64], cur[64], gb[64], sflags[2];
  __shared__ unsigned int ebuf[BIN_CHUNK];  // 12.5 KB
  const int tid = threadIdx.x;
  const int bid = blockIdx.x;
  if (tid < 64) {
    unsigned long long m1 = __ballot(ei_i[2 * tid + 1] != 0);
    int ex = (x16[2 * tid] >> 7) & 0xFF;
    unsigned long long m2 = __ballot(ex >= 90 && ex <= 140);
    if (tid == 0) {
      sflags[0] = (m1 == 0ull) ? 1 : 0;
      sflags[1] = (__popcll(m2) >= 48) ? 1 : 0;
    }
    cnt[tid] = 0;
    cur[tid] = 0;
  }
  __syncthreads();
  const int is64 = sflags[0], isbf = sflags[1];
  if (bid == 0 && tid == 0) { flags[0] = is64; flags[1] = isbf; }
  if (bid < 128) {  // W swizzle side-job
    const void* W = bid < 64 ? W1 : W2;
    unsigned short* wp = bid < 64 ? wp1 : wp2;
    int idx = (bid & 63) * 256 + tid;
    int k = idx >> 7, n = idx & 127;
    wp[(k >> 3) * 1024 + n * 8 + (k & 7)] = (unsigned short)f2bs(ldf(W, idx, isbf));
  }
  const void* ei = (const void*)ei_i;
  const int e0 = bid * BIN_CHUNK;
  for (int t = tid; t < BIN_CHUNK; t += 256) {
    int s = lde(ei, (size_t)(e0 + t), is64);
    int d = lde(ei, (size_t)NE + e0 + t, is64);
    ebuf[t] = ((unsigned)s << 16) | ((unsigned)(d >> 10) << 10) | (unsigned)(d & 1023);
    atomicAdd(&cnt[d >> 10], 1);
  }
  __syncthreads();
  if (tid < 64 && cnt[tid] > 0) gb[tid] = tid * CAP + atomicAdd(&tailc[tid], cnt[tid]);
  __syncthreads();
  for (int t = tid; t < BIN_CHUNK; t += 256) {
    unsigned int u = ebuf[t];
    int b = (int)((u >> 10) & 63);
    int r = atomicAdd(&cur[b], 1);
    binned[gb[b] + r] = u;
  }
}

// Per-bucket: degree hist (LDS) -> dinv/rowptr/rowend, then exact CSR fill
// with LDS cursors. 49 blocks x 1024. packed u: s=u>>16, dlow=u&1023.
__global__ __launch_bounds__(1024) void k_degfill(const unsigned int* binned, const int* tailc,
                                                  float* dinv, int* rowptr, int* rowend,
                                                  int* csr_src) {
  __shared__ int hist[1024];
  const int b = blockIdx.x;
  const int t = threadIdx.x;
  hist[t] = 0;
  __syncthreads();
  const int eb = b * CAP, ee = eb + tailc[b];
  for (int e = eb + t; e < ee; e += 1024) atomicAdd(&hist[binned[e] & 1023], 1);
  __syncthreads();
  int h = hist[t];
  __syncthreads();
  for (int off = 1; off < 1024; off <<= 1) {  // inclusive scan
    int u = (t >= off) ? hist[t - off] : 0;
    __syncthreads();
    hist[t] += u;
    __syncthreads();
  }
  int start = eb + hist[t] - h;  // exclusive prefix, global position
  int node = b * 1024 + t;
  if (node < NN) {
    rowptr[node] = start;
    rowend[node] = start + h;
    dinv[node] = rsqrtf((float)(h + 1));  // +1 self-loop
  }
  __syncthreads();
  hist[t] = start;  // repurpose as fill cursor
  __syncthreads();
  for (int e = eb + t; e < ee; e += 1024) {
    unsigned int u = binned[e];
    int pos = atomicAdd(&hist[u & 1023], 1);
    csr_src[pos] = (int)(u >> 16);
  }
}

// MFMA GEMM, 64 rows/block (782 blocks). out = dinv-prescaled bf16 in
// packed-slot layout: row r, u32 slot s holds bf16 pair (col s, col s+64).
// W pre-swizzled (wp), raw LDS copy. XMODE 0: layer-1 input (probe f32/bf16).
// XMODE 2: aggbuf bf16 + fused BN1 (stats from 64-copy partials statsp).
// Blocks 0..63 zero zstats (consumed by the NEXT kernel's atomics --
// stream-ordered, safe).
template <int XMODE>
__global__ __launch_bounds__(256) void k_gemm(const void* in_, const unsigned short* wp,
                                              const int* flags, const float* dinv,
                                              const float* statsp, const void* g,
                                              const void* be, const void* al,
                                              float* zstats, unsigned int* out) {
  __shared__ alignas(16) short sW[16 * 128 * 8];  // 32 KB
  __shared__ float sSc[DD], sSh[DD], sAl;
  const int isbf = flags[1];
  const int tid = threadIdx.x;

  if (blockIdx.x < 64) zstats[blockIdx.x * 256 + tid] = 0.f;
  {
    const short8* src = (const short8*)wp;
    short8* dst = (short8*)sW;
#pragma unroll
    for (int i = 0; i < 8; i++) dst[tid + i * 256] = src[tid + i * 256];
  }
  if (XMODE == 2) {
    if (tid < DD) {
      float s = 0.f, q = 0.f;
#pragma unroll 8
      for (int k = 0; k < 64; k++) {
        s += statsp[k * 256 + tid];
        q += statsp[k * 256 + 128 + tid];
      }
      const float inv_n = 1.0f / NN;
      float mu = s * inv_n;
      float var = q * inv_n - mu * mu;
      float sc = rsqrtf(var + BN_EPS) * ldf(g, tid, isbf);
      sSc[tid] = sc;
      sSh[tid] = ldf(be, tid, isbf) - mu * sc;
    }
    if (tid == 0) sAl = ldf(al, 0, isbf);
  }
  __syncthreads();

  const int wave = tid >> 6;
  const int lane = tid & 63;
  const int quad = lane >> 4;
  const int m16 = lane & 15;
  const int r0 = blockIdx.x * 64 + wave * 16;

  f32x4 acc[8];
#pragma unroll
  for (int n = 0; n < 8; n++) acc[n] = (f32x4){0.f, 0.f, 0.f, 0.f};

#pragma unroll
  for (int q = 0; q < 4; q++) {
    const int kq = q * 32 + quad * 8;
    short8 af;
    {
      int row = r0 + m16;
      row = row < NN ? row : NN - 1;  // clamp; garbage rows never stored
      if (XMODE == 2) {
        short8 raw = *(const short8*)((const short*)in_ + (size_t)row * DD + kq);
        short8 f;
#pragma unroll
        for (int jj = 0; jj < 8; jj++) {
          float y = s2f(raw[jj]);
          y = y * sSc[kq + jj] + sSh[kq + jj];
          y = y > 0.f ? y : sAl * y;
          f[jj] = (short)f2bs(y);
        }
        af = f;
      } else if (isbf) {
        af = *(const short8*)((const short*)in_ + (size_t)row * DD + kq);
      } else {
        const float* ap = (const float*)in_ + (size_t)row * DD + kq;
        const float4 u0 = *(const float4*)ap;
        const float4 u1 = *(const float4*)(ap + 4);
        float v[8] = {u0.x, u0.y, u0.z, u0.w, u1.x, u1.y, u1.z, u1.w};
        short8 f;
#pragma unroll
        for (int jj = 0; jj < 8; jj++) f[jj] = (short)f2bs(v[jj]);
        af = f;
      }
    }
    const int c = q * 4 + quad;
    const short* bp = sW + c * 1024 + m16 * 8;
#pragma unroll
    for (int n = 0; n < 8; n++) {
      const short8 bfrag = *(const short8*)(bp + n * 128);
      acc[n] = __builtin_amdgcn_mfma_f32_16x16x32_bf16(af, bfrag, acc[n], 0, 0, 0);
    }
  }

#pragma unroll
  for (int r = 0; r < 4; r++) {
    int row = r0 + quad * 4 + r;
    if (row < NN) {
      float di = dinv[row];
      unsigned int* orow = out + (size_t)row * 64;
#pragma unroll
      for (int n = 0; n < 4; n++) {
        unsigned int p = (f2bs(di * acc[n + 4][r]) << 16) | f2bs(di * acc[n][r]);
        orow[n * 16 + m16] = p;
      }
    }
  }
}

// One wave per node (12500 blocks = 50000 waves exactly). Row range
// [rowptr[w], rowend[w]) in the gapped CSR via readfirstlane -> scalar pipe.
// Main loop: 16-deep gather window. Remainder r in [1,16): ONE predicated
// 16-deep batch (index clamp e+(k<r?k:0); dup addrs = cache hits; masked
// branch-free accumulate) instead of serial 4-deep/1-deep tails.
__global__ __launch_bounds__(256) void k_agg(const unsigned int* hs, const float* dinv,
                                             const int* rowptr, const int* rowend,
                                             const int* csr_src, const void* bias,
                                             const int* flags, unsigned short* out,
                                             float* statsp) {
  const int tid = threadIdx.x;
  const int w = (blockIdx.x * 256 + tid) >> 6;   // never >= NN (12500*4 == NN)
  const int lane = tid & 63;
  const float dd_ = dinv[w];
  unsigned int hv = hs[(size_t)w * 64 + lane];
  float ax = bslo(hv), ay = bshi(hv);
  int e = __builtin_amdgcn_readfirstlane(rowptr[w]);
  const int e1 = __builtin_amdgcn_readfirstlane(rowend[w]);

  for (; e + 16 <= e1; e += 16) {
    int s[16];
#pragma unroll
    for (int k = 0; k < 16; k++) s[k] = csr_src[e + k];
    unsigned int v[16];
#pragma unroll
    for (int k = 0; k < 16; k++) v[k] = hs[(size_t)s[k] * 64 + lane];
#pragma unroll
    for (int k = 0; k < 16; k++) { ax += bslo(v[k]); ay += bshi(v[k]); }
  }
  const int r = e1 - e;  // 0..15, wave-uniform
  if (r > 0) {
    int s[16];
#pragma unroll
    for (int k = 0; k < 16; k++) s[k] = csr_src[e + (k < r ? k : 0)];
    unsigned int v[16];
#pragma unroll
    for (int k = 0; k < 16; k++) v[k] = hs[(size_t)s[k] * 64 + lane];
#pragma unroll
    for (int k = 0; k < 16; k++) {
      const float m = (k < r) ? 1.f : 0.f;
      ax += m * bslo(v[k]);
      ay += m * bshi(v[k]);
    }
  }

  int isbf = flags[1];
  float o1 = dd_ * ax + ldf(bias, lane, isbf);
  float o2 = dd_ * ay + ldf(bias, lane + 64, isbf);
  unsigned short* orow = out + (size_t)w * DD;
  orow[lane] = (unsigned short)f2bs(o1);
  orow[lane + 64] = (unsigned short)f2bs(o2);

  __shared__ float rs1[256], rq1[256], rs2[256], rq2[256];
  rs1[tid] = o1; rq1[tid] = o1 * o1;
  rs2[tid] = o2; rq2[tid] = o2 * o2;
  __syncthreads();
  float* p = statsp + (blockIdx.x & 63) * 256;
  if (tid < 64) {  // col tid
    float s = rs1[tid] + rs1[tid + 64] + rs1[tid + 128] + rs1[tid + 192];
    float q = rq1[tid] + rq1[tid + 64] + rq1[tid + 128] + rq1[tid + 192];
    atomicAdd(&p[tid], s);
    atomicAdd(&p[128 + tid], q);
  } else if (tid < 128) {  // col tid (= 64 + lane)
    int l = tid - 64;
    float s = rs2[l] + rs2[l + 64] + rs2[l + 128] + rs2[l + 192];
    float q = rq2[l] + rq2[l + 64] + rq2[l + 128] + rq2[l + 192];
    atomicAdd(&p[tid], s);
    atomicAdd(&p[128 + tid], q);
  }
}

// Final BN+PReLU: 1024 grid-stride blocks. Prologue sums the 64 stat copies
// into LDS sc/sh (one rsqrt per column per block, not per element).
__global__ __launch_bounds__(256) void k_bn_apply(const unsigned int* x32, const float* statsp,
                                                  const void* g, const void* be, const void* al,
                                                  const int* flags, void* out) {
  __shared__ float sSc[DD], sSh[DD], sAl;
  const int tid = threadIdx.x;
  const int isbf = flags[1];
  if (tid < DD) {
    float s = 0.f, q = 0.f;
#pragma unroll 8
    for (int k = 0; k < 64; k++) {
      s += statsp[k * 256 + tid];
      q += statsp[k * 256 + 128 + tid];
    }
    const float inv_n = 1.0f / NN;
    float mu = s * inv_n;
    float var = q * inv_n - mu * mu;
    float sc = rsqrtf(var + BN_EPS) * ldf(g, tid, isbf);
    sSc[tid] = sc;
    sSh[tid] = ldf(be, tid, isbf) - mu * sc;
  }
  if (tid == 0) sAl = ldf(al, 0, isbf);
  __syncthreads();
  const float alpha = sAl;
  for (int i4 = blockIdx.x * 256 + tid; i4 < NN * 32; i4 += gridDim.x * 256) {
    int jq = (i4 & 31) * 4;
    const uint2 xv = ((const uint2*)x32)[i4];
    float xa[4] = {bslo(xv.x), bshi(xv.x), bslo(xv.y), bshi(xv.y)};
    float y[4];
#pragma unroll
    for (int u = 0; u < 4; u++) {
      int j = jq + u;
      float v = xa[u] * sSc[j] + sSh[j];
      y[u] = v > 0.f ? v : alpha * v;
    }
    if (isbf) {
      uint2 o;
      o.x = (f2bs(y[1]) << 16) | f2bs(y[0]);
      o.y = (f2bs(y[3]) << 16) | f2bs(y[2]);
      ((uint2*)out)[i4] = o;
    } else {
      float4 o = {y[0], y[1], y[2], y[3]};
      ((float4*)out)[i4] = o;
    }
  }
}

extern "C" void kernel_launch(void* const* d_in, const int* in_sizes, int n_in,
                              void* d_out, int out_size, void* d_ws, size_t ws_size,
                              hipStream_t stream) {
  const void* x = d_in[0];
  const int* ei = (const int*)d_in[1];
  const void* W1 = d_in[2];
  const void* b1 = d_in[3];
  const void* g1 = d_in[4];
  const void* be1 = d_in[5];
  const void* a1 = d_in[6];
  const void* W2 = d_in[7];
  const void* b2 = d_in[8];
  const void* g2 = d_in[9];
  const void* be2 = d_in[10];
  const void* a2 = d_in[11];

  char* w = (char*)d_ws;
  float* dinv = (float*)w;                              // 200000
  int* flags = (int*)(w + 200704);                      // 8
  int* rowptr = (int*)(w + 404800);                     // 200000
  int* rowend = (int*)(w + 604816);                     // 200000
  int* tailc = (int*)(w + 805632);                      // 256
  float* stats1p = (float*)(w + 806400);                // 65536
  float* stats2p = (float*)(w + 871936);                // 65536
  int* csr_src = (int*)(w + 1048576);                   // 3612672
  unsigned int* hbuf = (unsigned int*)(w + 4718592);    // 12800000
  unsigned short* wp1 = (unsigned short*)(w + 17518592);   // 32768
  unsigned short* wp2 = (unsigned short*)(w + 17551360);   // 32768
  unsigned short* aggbuf = (unsigned short*)(w + 30056448);  // 12800000
  unsigned int* binned = (unsigned int*)(w + 42856448);  // 3612672

  const int NB_G = (NN + 63) / 64;     // 782
  const int NB_W = NN * 64 / 256;      // 12500

  hipMemsetAsync(tailc, 0, 256, stream);
  k_bin<<<dim3(256), dim3(256), 0, stream>>>(ei, (const unsigned short*)x, W1, W2,
                                             wp1, wp2, flags, tailc, binned);
  k_degfill<<<dim3(NBKT), dim3(1024), 0, stream>>>(binned, tailc, dinv, rowptr, rowend,
                                                   csr_src);

  // ---- layer 1 ----
  k_gemm<0><<<dim3(NB_G), dim3(256), 0, stream>>>(x, wp1, flags, dinv,
                                                  nullptr, nullptr, nullptr, nullptr,
                                                  stats1p, hbuf);
  k_agg<<<dim3(NB_W), dim3(256), 0, stream>>>(hbuf, dinv, rowptr, rowend, csr_src,
                                              b1, flags, aggbuf, stats1p);

  // ---- layer 2 (BN1+PReLU fused into GEMM A-path via stats1p) ----
  k_gemm<2><<<dim3(NB_G), dim3(256), 0, stream>>>(aggbuf, wp2, flags, dinv,
                                                  stats1p, g1, be1, a1, stats2p, hbuf);
  k_agg<<<dim3(NB_W), dim3(256), 0, stream>>>(hbuf, dinv, rowptr, rowend, csr_src,
                                              b2, flags, aggbuf, stats2p);
  k_bn_apply<<<dim3(1024), dim3(256), 0, stream>>>((const unsigned int*)aggbuf, stats2p,
                                                   g2, be2, a2, flags, d_out);
}